// Round 6
// baseline (253.898 us; speedup 1.0000x reference)
//
#include <hip/hip_runtime.h>

#define NTOT 9216
#define NORMC 0.42044820762685725f   /* 32^-0.25 */
#define RATIO 0.08838834764831845f   /* 128^-0.5 */
#define FEPS 1e-4f

typedef _Float16 h8 __attribute__((ext_vector_type(8)));
typedef _Float16 h4 __attribute__((ext_vector_type(4)));
typedef float f4 __attribute__((ext_vector_type(4)));

// async global->LDS, 16B/lane; lds dest = wave-uniform base + lane*16
__device__ __forceinline__ void gld16(const _Float16* g, _Float16* l) {
  __builtin_amdgcn_global_load_lds((const __attribute__((address_space(1))) void*)g,
                                   (__attribute__((address_space(3))) void*)l, 16, 0, 0);
}

// ---------------------------------------------------------------- fused prep
// r < 2304: x transpose tiles; then Wall rows; projh; Wc rows; ctxTf zeroing.
__global__ __launch_bounds__(256) void prep(
    const float* __restrict__ x, const float* __restrict__ wq,
    const float* __restrict__ wk, const float* __restrict__ wv,
    const float* __restrict__ proj, const float* __restrict__ wo,
    const float* __restrict__ bo, const float* __restrict__ wp,
    const float* __restrict__ bp, _Float16* __restrict__ xT,
    _Float16* __restrict__ Wall, _Float16* __restrict__ projh,
    _Float16* __restrict__ Wc, float* __restrict__ bc,
    float* __restrict__ ctxTf) {
  __shared__ float T_s[64][65];
  int r = blockIdx.x, t = threadIdx.x;
  if (r < 2304) {
    int nx = r % 144, rem = r / 144;
    int cy = rem & 3, b = rem >> 2;
    int n0 = nx * 64, c0 = cy * 64;
    for (int i = 0; i < 4; ++i) {
      int f = t + i * 256;
      int cc = f >> 4, n4 = f & 15;
      float4 a = *(const float4*)(x + ((size_t)(b * 256 + c0 + cc)) * NTOT + n0 + n4 * 4);
      T_s[cc][n4 * 4 + 0] = a.x;
      T_s[cc][n4 * 4 + 1] = a.y;
      T_s[cc][n4 * 4 + 2] = a.z;
      T_s[cc][n4 * 4 + 3] = a.w;
    }
    __syncthreads();
    for (int i = 0; i < 2; ++i) {
      int f = t + i * 256;
      int nn = f >> 3, c8 = f & 7;
      h8 hv;
      for (int j = 0; j < 8; ++j) hv[j] = (_Float16)T_s[c8 * 8 + j][nn];
      *(h8*)(xT + ((size_t)(b * NTOT + n0 + nn)) * 256 + c0 + c8 * 8) = hv;
    }
    return;
  }
  int r2 = r - 2304;
  if (r2 < 768) {
    const float* src = (r2 < 256) ? wq + (size_t)r2 * 256
                     : (r2 < 512) ? wk + (size_t)(r2 - 256) * 256
                                  : wv + (size_t)(r2 - 512) * 256;
    Wall[(size_t)r2 * 256 + t] = (_Float16)src[t];
  } else if (r2 < 784) {
    int idx = (r2 - 768) * 256 + t;
    projh[idx] = (_Float16)proj[idx];
  } else if (r2 < 1040) {
    int o = r2 - 784;
    float acc = 0.f;
    for (int c = 0; c < 256; ++c) acc += wp[o * 256 + c] * wo[c * 256 + t];
    Wc[o * 256 + t] = (_Float16)acc;
    if (t == 0) {
      float ab = bp[o];
      for (int c = 0; c < 256; ++c) ab += wp[o * 256 + c] * bo[c];
      bc[o] = ab;
    }
  } else {
    // zero the ctx accumulator: 132 blocks x 1024 floats = 135,168 = 32*4224
    int z = r2 - 1040;
    float4 zz = make_float4(0.f, 0.f, 0.f, 0.f);
    *(float4*)(ctxTf + (size_t)z * 1024 + t * 4) = zz;
  }
}

// ---------------------------------------------------------------- qkv MFMA gemm
// R0-proven structure (80 VGPR, 4 blocks/CU). 1D grid with XCD co-location:
// the 6 blocks sharing one xT tile (2 co-halves x 3 sels) occupy 6
// CONSECUTIVE slots on ONE XCD -> tile fetched once into that XCD's L2.
__global__ __launch_bounds__(256) void qkv_mfma(
    const _Float16* __restrict__ xT, const _Float16* __restrict__ Wall,
    const _Float16* __restrict__ projh, _Float16* __restrict__ q,
    _Float16* __restrict__ k, _Float16* __restrict__ vT,
    float* __restrict__ kmaxp) {
  __shared__ __align__(16) _Float16 A_s[128 * 32];
  __shared__ __align__(16) _Float16 B_s[128 * 32];
  __shared__ __align__(16) _Float16 ktile[64 * 132];
  int id = blockIdx.x;
  int xcd = id & 7, slot = id >> 3;      // 216 slots per XCD
  int bx = xcd * 36 + slot / 6;          // xT tile 0..287
  int variant = slot % 6;                // 6 sharers adjacent on this XCD
  int sel = variant % 3;
  int co0 = (variant / 3) * 128;
  int b = bx / 72, ntile = bx % 72;
  int n0 = bx * 128;
  const _Float16* Wb = Wall + (size_t)sel * 65536;
  int t = threadIdx.x, wave = t >> 6, lane = t & 63;
  int lm = lane & 15, lg = lane >> 4;
  int wm = (wave & 1) * 64, wn = (wave >> 1) * 64;
  int srow = wave * 32 + (lane >> 2);
  int scol = ((lane & 3) ^ ((lane >> 3) & 3)) * 8;
  const _Float16* gA = Wb + (size_t)(co0 + srow) * 256 + scol;
  const _Float16* gB = xT + (size_t)(n0 + srow) * 256 + scol;
  _Float16* lA = A_s + wave * 1024;
  _Float16* lB = B_s + wave * 1024;
  int pg = (lg ^ ((lm >> 1) & 3)) * 8;
  f4 acc[4][4] = {};
  if (sel < 2) {
    for (int kt = 0; kt < 8; ++kt) {
      int c0 = kt * 32;
      __syncthreads();
      gld16(gA + c0, lA);
      gld16(gA + c0 + 16 * 256, lA + 512);
      gld16(gB + c0, lB);
      gld16(gB + c0 + 16 * 256, lB + 512);
      __syncthreads();
      h8 a[4], bf[4];
#pragma unroll
      for (int mi = 0; mi < 4; ++mi) a[mi] = *(const h8*)&A_s[(wm + mi * 16 + lm) * 32 + pg];
#pragma unroll
      for (int ni = 0; ni < 4; ++ni) bf[ni] = *(const h8*)&B_s[(wn + ni * 16 + lm) * 32 + pg];
#pragma unroll
      for (int mi = 0; mi < 4; ++mi)
#pragma unroll
        for (int ni = 0; ni < 4; ++ni)
          acc[mi][ni] = __builtin_amdgcn_mfma_f32_16x16x32_f16(a[mi], bf[ni], acc[mi][ni], 0, 0, 0);
    }
    _Float16* Out = (sel == 0) ? q : k;
#pragma unroll
    for (int mi = 0; mi < 4; ++mi)
#pragma unroll
      for (int ni = 0; ni < 4; ++ni) {
        h4 hv;
#pragma unroll
        for (int r = 0; r < 4; ++r) hv[r] = (_Float16)acc[mi][ni][r];
        *(h4*)(Out + (size_t)(n0 + wn + ni * 16 + lm) * 256 + co0 + wm + mi * 16 + lg * 4) = hv;
      }
    if (sel == 1) {
      h8 pr[8];
#pragma unroll
      for (int mt = 0; mt < 8; ++mt)
        pr[mt] = *(const h8*)&projh[(mt * 16 + lm) * 32 + lg * 8];
      float vmax = -1e30f;
      for (int half = 0; half < 2; ++half) {
        __syncthreads();
        if ((wave >> 1) == half) {
#pragma unroll
          for (int mi = 0; mi < 4; ++mi)
#pragma unroll
            for (int ni = 0; ni < 4; ++ni) {
              h4 hv;
#pragma unroll
              for (int r = 0; r < 4; ++r) hv[r] = (_Float16)acc[mi][ni][r];
              *(h4*)&ktile[(ni * 16 + lm) * 132 + wm + mi * 16 + lg * 4] = hv;
            }
        }
        __syncthreads();
#pragma unroll
        for (int nt2 = 0; nt2 < 4; ++nt2) {
          h8 a = *(const h8*)&ktile[(nt2 * 16 + lm) * 132 + wave * 32 + lg * 8];
#pragma unroll
          for (int mt = 0; mt < 8; ++mt) {
            f4 z = {0.f, 0.f, 0.f, 0.f};
            f4 d = __builtin_amdgcn_mfma_f32_16x16x32_f16(a, pr[mt], z, 0, 0, 0);
            vmax = fmaxf(vmax, fmaxf(fmaxf(d[0], d[1]), fmaxf(d[2], d[3])));
          }
        }
      }
      for (int i = 1; i < 64; i <<= 1) vmax = fmaxf(vmax, __shfl_xor(vmax, i, 64));
      if (lane == 0) {
        int h = (co0 >> 5) + wave;
        kmaxp[(size_t)(b * 8 + h) * 72 + ntile] = NORMC * vmax;
      }
    }
  } else {
    for (int kt = 0; kt < 8; ++kt) {
      int c0 = kt * 32;
      __syncthreads();
      gld16(gA + c0, lA);
      gld16(gA + c0 + 16 * 256, lA + 512);
      gld16(gB + c0, lB);
      gld16(gB + c0 + 16 * 256, lB + 512);
      __syncthreads();
      h8 a[4], bf[4];
#pragma unroll
      for (int mi = 0; mi < 4; ++mi) a[mi] = *(const h8*)&A_s[(wm + mi * 16 + lm) * 32 + pg];
#pragma unroll
      for (int ni = 0; ni < 4; ++ni) bf[ni] = *(const h8*)&B_s[(wn + ni * 16 + lm) * 32 + pg];
#pragma unroll
      for (int mi = 0; mi < 4; ++mi)
#pragma unroll
        for (int ni = 0; ni < 4; ++ni)
          acc[mi][ni] = __builtin_amdgcn_mfma_f32_16x16x32_f16(bf[ni], a[mi], acc[mi][ni], 0, 0, 0);
    }
#pragma unroll
    for (int mi = 0; mi < 4; ++mi)
#pragma unroll
      for (int ni = 0; ni < 4; ++ni) {
        h4 hv;
#pragma unroll
        for (int r = 0; r < 4; ++r) hv[r] = (_Float16)acc[mi][ni][r];
        *(h4*)(vT + ((size_t)(b * 256 + co0 + wm + mi * 16 + lm)) * NTOT +
               ntile * 128 + wn + ni * 16 + lg * 4) = hv;
      }
  }
}

// ---------------------------------------------------------------- ctx: partials
// Accumulate directly into ctxTf [bh][33][128] f32 via device-scope atomics
// (rows 0..31 = sum_n kp[n][m] v[n][d]; row 32 = sum_n kp). L2-resident
// 540 KB target, 24-way contention per cell — replaces the 13 MB part
// buffer + reduce_ctx kernel entirely.
__global__ __launch_bounds__(256) void ctx_mfma(
    const _Float16* __restrict__ k, const _Float16* __restrict__ vT,
    const _Float16* __restrict__ projh, const float* __restrict__ kmaxp,
    float* __restrict__ ctxTf) {
  __shared__ __align__(16) _Float16 k_s[128 * 32];
  __shared__ __align__(16) _Float16 vT_s[32 * 136];
  __shared__ __align__(16) _Float16 kpT[128 * 136];
  __shared__ float diag_s[128];
  __shared__ float kmax_sh;
  int id = blockIdx.x;
  int xcd = id & 7, slot = id >> 3;      // 96 slots per XCD
  int grp = xcd * 12 + slot / 8;         // 0..95 = nx + 24*b
  int h = slot % 8;
  int nx = grp % 24, b = grp / 24;
  int bh = b * 8 + h;
  int nbase = nx * 384;
  int t = threadIdx.x, wave = t >> 6, lane = t & 63, lm = lane & 15, lg = lane >> 4;
  h8 pr[8];
#pragma unroll
  for (int mt = 0; mt < 8; ++mt) pr[mt] = *(const h8*)&projh[(mt * 16 + lm) * 32 + lg * 8];
  int scol = ((lane & 3) ^ ((lane >> 3) & 3)) * 8;
  const _Float16* gK =
      k + ((size_t)(b * NTOT + nbase + wave * 32 + (lane >> 2))) * 256 + h * 32 + scol;
  const _Float16* gV = vT + ((size_t)(b * 256 + h * 32 + (t >> 3))) * NTOT + nbase;
  _Float16* lK = k_s + wave * 1024;
  int vd = t >> 3, vg = t & 7;
  // prologue: stage K chunk 0 + gV chunk 0 -> regs (overlaps kmax reduction)
  gld16(gK, lK);
  gld16(gK + 16 * 256, lK + 512);
  h8 vr0 = *(const h8*)(gV + vg * 8);
  h8 vr1 = *(const h8*)(gV + 64 + vg * 8);
  {
    float* kred = (float*)kpT;
    if (t < 72) kred[t] = kmaxp[(size_t)bh * 72 + t];
    __syncthreads();
    if (t == 0) {
      float mx = -1e30f;
      for (int i = 0; i < 72; ++i) mx = fmaxf(mx, kred[i]);
      kmax_sh = mx;
    }
    __syncthreads();
  }
  float kmax = kmax_sh;
  int pg = (lg ^ ((lm >> 1) & 3)) * 8;
  f4 cacc[2][2] = {};
  float ks[8] = {};
#pragma unroll 1
  for (int ch = 0; ch < 3; ++ch) {
    *(h8*)&vT_s[vd * 136 + vg * 8] = vr0;
    *(h8*)&vT_s[vd * 136 + 64 + vg * 8] = vr1;
    asm volatile("s_waitcnt vmcnt(0) lgkmcnt(0)" ::: "memory");  // A: k_s + vT_s ready
    __builtin_amdgcn_s_barrier();
    __builtin_amdgcn_sched_barrier(0);
    if (t < 128) {
      float s = 0.f;
#pragma unroll
      for (int c = 0; c < 4; ++c) {
        h8 kv = *(const h8*)&k_s[t * 32 + c * 8];
#pragma unroll
        for (int j = 0; j < 8; ++j) s += (float)kv[j] * (float)kv[j];
      }
      diag_s[t] = s * (0.5f * NORMC * NORMC);
    }
    f4 dsh[2][8];
#pragma unroll
    for (int nt = 0; nt < 2; ++nt) {
      h8 a = *(const h8*)&k_s[(wave * 32 + nt * 16 + lm) * 32 + pg];
#pragma unroll
      for (int mt = 0; mt < 8; ++mt) {
        f4 z = {0.f, 0.f, 0.f, 0.f};
        dsh[nt][mt] = __builtin_amdgcn_mfma_f32_16x16x32_f16(a, pr[mt], z, 0, 0, 0);
      }
    }
    asm volatile("s_waitcnt lgkmcnt(0)" ::: "memory");  // B: k_s reads + diag write done
    __builtin_amdgcn_s_barrier();
    __builtin_amdgcn_sched_barrier(0);
    if (ch < 2) {  // prefetch next K chunk + next gV (in flight across C, D)
      gld16(gK + (size_t)((ch + 1) * 128) * 256, lK);
      gld16(gK + (size_t)((ch + 1) * 128) * 256 + 16 * 256, lK + 512);
      vr0 = *(const h8*)(gV + (ch + 1) * 128 + vg * 8);
      vr1 = *(const h8*)(gV + (ch + 1) * 128 + 64 + vg * 8);
    }
#pragma unroll
    for (int nt = 0; nt < 2; ++nt)
#pragma unroll
      for (int mt = 0; mt < 8; ++mt) {
        h4 hv;
        float lsum = 0.f;
#pragma unroll
        for (int r = 0; r < 4; ++r) {
          int nl = wave * 32 + nt * 16 + lg * 4 + r;
          float val = RATIO * (__expf(NORMC * dsh[nt][mt][r] - diag_s[nl] - kmax) + FEPS);
          hv[r] = (_Float16)val;
          lsum += val;
        }
        ks[mt] += lsum;
        *(h4*)&kpT[(mt * 16 + lm) * 136 + wave * 32 + nt * 16 + lg * 4] = hv;
      }
    asm volatile("s_waitcnt lgkmcnt(0)" ::: "memory");  // C: kpT visible; vm untouched
    __builtin_amdgcn_s_barrier();
    __builtin_amdgcn_sched_barrier(0);
#pragma unroll
    for (int k2 = 0; k2 < 4; ++k2) {
      h8 a2[2], b2[2];
#pragma unroll
      for (int mt2 = 0; mt2 < 2; ++mt2)
        a2[mt2] = *(const h8*)&kpT[(wave * 32 + mt2 * 16 + lm) * 136 + k2 * 32 + lg * 8];
#pragma unroll
      for (int dt = 0; dt < 2; ++dt)
        b2[dt] = *(const h8*)&vT_s[(dt * 16 + lm) * 136 + k2 * 32 + lg * 8];
#pragma unroll
      for (int mt2 = 0; mt2 < 2; ++mt2)
#pragma unroll
        for (int dt = 0; dt < 2; ++dt)
          cacc[mt2][dt] =
              __builtin_amdgcn_mfma_f32_16x16x32_f16(a2[mt2], b2[dt], cacc[mt2][dt], 0, 0, 0);
    }
    __builtin_amdgcn_s_barrier();  // D: PV reads consumed before vT_s restage
  }
  float* pp = ctxTf + (size_t)bh * 4224;
#pragma unroll
  for (int mt2 = 0; mt2 < 2; ++mt2)
#pragma unroll
    for (int dt = 0; dt < 2; ++dt) {
      int base = (dt * 16 + lm) * 128 + wave * 32 + mt2 * 16 + lg * 4;
#pragma unroll
      for (int r = 0; r < 4; ++r) atomicAdd(pp + base + r, cacc[mt2][dt][r]);
    }
#pragma unroll
  for (int mt = 0; mt < 8; ++mt) {
    float s = ks[mt];
    s += __shfl_xor(s, 16, 64);
    s += __shfl_xor(s, 32, 64);
    if (lg == 0) atomicAdd(pp + 4096 + mt * 16 + lm, s);
  }
}

// ---------------------------------------------------------------- q side
// XCD co-location: 8 heads of one (b, n-tile) — sharing q rows — adjacent
// on one XCD. Reads the f32 ctxTf accumulator directly (converts inline).
__global__ __launch_bounds__(256) void attn_mfma(
    const _Float16* __restrict__ q, const _Float16* __restrict__ projh,
    const float* __restrict__ ctxTf, _Float16* __restrict__ attn) {
  __shared__ __align__(16) _Float16 q_sh[128 * 32];
  __shared__ __align__(16) _Float16 qp_s[128 * 136];
  __shared__ float ksum_s[128];
  int id = blockIdx.x;
  int xcd = id & 7, slot = id >> 3;      // 288 slots per XCD
  int grp = xcd * 36 + slot / 8;         // 0..287 = nb + 72*b
  int h = slot % 8;
  int nb = grp % 72, b = grp / 72;
  int bh = b * 8 + h;
  int n0 = nb * 128;
  int t = threadIdx.x, wave = t >> 6, lane = t & 63, lm = lane & 15, lg = lane >> 4;
  h8 pr[8];
#pragma unroll
  for (int mt = 0; mt < 8; ++mt) pr[mt] = *(const h8*)&projh[(mt * 16 + lm) * 32 + lg * 8];
  int scol = ((lane & 3) ^ ((lane >> 3) & 3)) * 8;
  const _Float16* gQ =
      q + ((size_t)(b * NTOT + n0 + wave * 32 + (lane >> 2))) * 256 + h * 32 + scol;
  gld16(gQ, q_sh + wave * 1024);
  gld16(gQ + 16 * 256, q_sh + wave * 1024 + 512);
  const float* cb = ctxTf + (size_t)bh * 4224;
  h8 ac[2][4];
#pragma unroll
  for (int dt = 0; dt < 2; ++dt)
#pragma unroll
    for (int k2 = 0; k2 < 4; ++k2) {
      const float* p = cb + (dt * 16 + lm) * 128 + k2 * 32 + lg * 8;
      float4 u = *(const float4*)p;
      float4 v2 = *(const float4*)(p + 4);
      h8 hv;
      hv[0] = (_Float16)u.x;  hv[1] = (_Float16)u.y;
      hv[2] = (_Float16)u.z;  hv[3] = (_Float16)u.w;
      hv[4] = (_Float16)v2.x; hv[5] = (_Float16)v2.y;
      hv[6] = (_Float16)v2.z; hv[7] = (_Float16)v2.w;
      ac[dt][k2] = hv;
    }
  if (t < 128) ksum_s[t] = cb[4096 + t];
  __syncthreads();
  int pg = (lg ^ ((lm >> 1) & 3)) * 8;
  float diag_r[2];
#pragma unroll
  for (int nt = 0; nt < 2; ++nt) {
    int n = wave * 32 + nt * 16 + lm;
    float s = 0.f;
#pragma unroll
    for (int c = 0; c < 4; ++c) {
      h8 qv = *(const h8*)&q_sh[n * 32 + c * 8];
#pragma unroll
      for (int j = 0; j < 8; ++j) s += (float)qv[j] * (float)qv[j];
    }
    diag_r[nt] = s * (0.5f * NORMC * NORMC);
  }
  f4 dsh[2][8];
#pragma unroll
  for (int nt = 0; nt < 2; ++nt) {
    h8 qf = *(const h8*)&q_sh[(wave * 32 + nt * 16 + lm) * 32 + pg];
#pragma unroll
    for (int mt = 0; mt < 8; ++mt) {
      f4 z = {0.f, 0.f, 0.f, 0.f};
      dsh[nt][mt] = __builtin_amdgcn_mfma_f32_16x16x32_f16(pr[mt], qf, z, 0, 0, 0);
    }
  }
  float den_r[2];
#pragma unroll
  for (int nt = 0; nt < 2; ++nt) {
    float mx = -1e30f;
#pragma unroll
    for (int mt = 0; mt < 8; ++mt)
#pragma unroll
      for (int r = 0; r < 4; ++r) mx = fmaxf(mx, dsh[nt][mt][r]);
    mx = fmaxf(mx, __shfl_xor(mx, 16, 64));
    mx = fmaxf(mx, __shfl_xor(mx, 32, 64));
    float den = 0.f;
#pragma unroll
    for (int mt = 0; mt < 8; ++mt) {
      h4 hv;
#pragma unroll
      for (int r = 0; r < 4; ++r) {
        float val = RATIO * (__expf(NORMC * (dsh[nt][mt][r] - mx) - diag_r[nt]) + FEPS);
        hv[r] = (_Float16)val;
        den += val * ksum_s[mt * 16 + lg * 4 + r];
      }
      *(h4*)&qp_s[(wave * 32 + nt * 16 + lm) * 136 + mt * 16 + lg * 4] = hv;
    }
    den += __shfl_xor(den, 16, 64);
    den += __shfl_xor(den, 32, 64);
    den_r[nt] = 1.f / den;
  }
  __syncthreads();
  f4 oacc[2][2] = {};
#pragma unroll
  for (int k2 = 0; k2 < 4; ++k2) {
    h8 bq[2];
#pragma unroll
    for (int nt = 0; nt < 2; ++nt)
      bq[nt] = *(const h8*)&qp_s[(wave * 32 + nt * 16 + lm) * 136 + k2 * 32 + lg * 8];
#pragma unroll
    for (int dt = 0; dt < 2; ++dt)
#pragma unroll
      for (int nt = 0; nt < 2; ++nt)
        oacc[dt][nt] = __builtin_amdgcn_mfma_f32_16x16x32_f16(ac[dt][k2], bq[nt], oacc[dt][nt], 0, 0, 0);
  }
#pragma unroll
  for (int dt = 0; dt < 2; ++dt)
#pragma unroll
    for (int nt = 0; nt < 2; ++nt) {
      int n = wave * 32 + nt * 16 + lm;
      h4 hv;
#pragma unroll
      for (int r = 0; r < 4; ++r) hv[r] = (_Float16)(oacc[dt][nt][r] * den_r[nt]);
      *(h4*)(attn + ((size_t)(b * NTOT + n0 + n)) * 256 + h * 32 + dt * 16 + lg * 4) = hv;
    }
}

// ---------------------------------------------------------------- output gemm
// T4 counted-vmcnt pipeline + XCD co-location of the 2 co-halves sharing
// one attn tile.
__global__ __launch_bounds__(256) void out_mfma(
    const _Float16* __restrict__ Wc, const _Float16* __restrict__ attn,
    const float* __restrict__ bc, float* __restrict__ out) {
  __shared__ __align__(16) _Float16 pool[16384];
  int id = blockIdx.x;
  int xcd = id & 7, slot = id >> 3;      // 72 slots per XCD
  int tile = xcd * 36 + slot / 2;        // 0..287
  int o0 = (slot & 1) * 128;
  int b = tile / 72, nb0 = (tile % 72) * 128;
  int t = threadIdx.x, wave = t >> 6, lane = t & 63;
  int lm = lane & 15, lg = lane >> 4;
  int wm = (wave & 1) * 64, wn = (wave >> 1) * 64;
  int srow = wave * 32 + (lane >> 2);
  int scol = ((lane & 3) ^ ((lane >> 3) & 3)) * 8;
  const _Float16* gA = Wc + (size_t)(o0 + srow) * 256 + scol;
  const _Float16* gB = attn + (size_t)(b * NTOT + nb0 + srow) * 256 + scol;
  int so = wave * 1024;
  int pg = (lg ^ ((lm >> 1) & 3)) * 8;
  f4 acc[4][4] = {};
  gld16(gA, pool + so);
  gld16(gA + 16 * 256, pool + so + 512);
  gld16(gB, pool + 8192 + so);
  gld16(gB + 16 * 256, pool + 8192 + so + 512);
#pragma unroll 1
  for (int kt = 0; kt < 8; ++kt) {
    int cur = (kt & 1) << 12;
    int nxt = cur ^ 4096;
    if (kt < 7) {
      int c0 = (kt + 1) * 32;
      gld16(gA + c0, pool + nxt + so);
      gld16(gA + c0 + 16 * 256, pool + nxt + so + 512);
      gld16(gB + c0, pool + 8192 + nxt + so);
      gld16(gB + c0 + 16 * 256, pool + 8192 + nxt + so + 512);
      asm volatile("s_waitcnt vmcnt(4)" ::: "memory");
    } else {
      asm volatile("s_waitcnt vmcnt(0)" ::: "memory");
    }
    __builtin_amdgcn_s_barrier();
    __builtin_amdgcn_sched_barrier(0);
    h8 a[4], bf[4];
#pragma unroll
    for (int mi = 0; mi < 4; ++mi)
      a[mi] = *(const h8*)&pool[cur + (wm + mi * 16 + lm) * 32 + pg];
#pragma unroll
    for (int ni = 0; ni < 4; ++ni)
      bf[ni] = *(const h8*)&pool[8192 + cur + (wn + ni * 16 + lm) * 32 + pg];
#pragma unroll
    for (int mi = 0; mi < 4; ++mi)
#pragma unroll
      for (int ni = 0; ni < 4; ++ni)
        acc[mi][ni] = __builtin_amdgcn_mfma_f32_16x16x32_f16(bf[ni], a[mi], acc[mi][ni], 0, 0, 0);
    __builtin_amdgcn_s_barrier();
  }
#pragma unroll
  for (int mi = 0; mi < 4; ++mi) {
    int o = o0 + wm + mi * 16 + lm;
    float bias = bc[o];
#pragma unroll
    for (int ni = 0; ni < 4; ++ni) {
      f4 ov = acc[mi][ni];
      float4 st = make_float4(ov[0] + bias, ov[1] + bias, ov[2] + bias, ov[3] + bias);
      *(float4*)(out + ((size_t)(b * 256 + o)) * NTOT + nb0 + wn + ni * 16 + lg * 4) = st;
    }
  }
}

// ---------------------------------------------------------------- launch
extern "C" void kernel_launch(void* const* d_in, const int* in_sizes, int n_in,
                              void* d_out, int out_size, void* d_ws, size_t ws_size,
                              hipStream_t stream) {
  const float* x = (const float*)d_in[0];
  const float* wq = (const float*)d_in[1];
  const float* wk = (const float*)d_in[2];
  const float* wv = (const float*)d_in[3];
  const float* wo = (const float*)d_in[4];
  const float* bo = (const float*)d_in[5];
  const float* proj = (const float*)d_in[6];
  const float* wp = (const float*)d_in[7];
  const float* bp = (const float*)d_in[8];
  float* out = (float*)d_out;
  float* ws = (float*)d_ws;

  float* ctxTf = ws;                       // 32*4224 = 135,168 f32 (zeroed by prep)
  float* kmaxp = ctxTf + 135168;           // 32*72 = 2304
  float* bc = kmaxp + 2304;                // 256
  _Float16* hb = (_Float16*)(bc + 256);
  const size_t THALF = (size_t)4 * NTOT * 256;  // 9,437,184
  _Float16* q_h = hb;
  _Float16* k_h = q_h + THALF;
  _Float16* xT = k_h + THALF;          // reused as attn fp16 output
  _Float16* vTg = xT + THALF;          // v transposed [b*256+c][n]
  _Float16* Wall = vTg + THALF;        // 768*256
  _Float16* Wc = Wall + 768 * 256;     // 256*256
  _Float16* projh = Wc + 65536;        // 128*32

  prep<<<3476, 256, 0, stream>>>(x, wq, wk, wv, proj, wo, bo, wp, bp,
                                 xT, Wall, projh, Wc, bc, ctxTf);
  qkv_mfma<<<1728, 256, 0, stream>>>(xT, Wall, projh, q_h, k_h, vTg, kmaxp);
  ctx_mfma<<<768, 256, 0, stream>>>(k_h, vTg, projh, kmaxp, ctxTf);
  attn_mfma<<<2304, 256, 0, stream>>>(q_h, projh, ctxTf, xT);
  out_mfma<<<576, 256, 0, stream>>>(Wc, xT, bc, out);
}

// Round 8
// 217.318 us; speedup vs baseline: 1.1683x; 1.1683x over previous
//
#include <hip/hip_runtime.h>

#define NTOT 9216
#define NORMC 0.42044820762685725f   /* 32^-0.25 */
#define RATIO 0.08838834764831845f   /* 128^-0.5 */
#define FEPS 1e-4f

typedef _Float16 h8 __attribute__((ext_vector_type(8)));
typedef _Float16 h4 __attribute__((ext_vector_type(4)));
typedef float f4 __attribute__((ext_vector_type(4)));

// async global->LDS, 16B/lane; lds dest = wave-uniform base + lane*16
__device__ __forceinline__ void gld16(const _Float16* g, _Float16* l) {
  __builtin_amdgcn_global_load_lds((const __attribute__((address_space(1))) void*)g,
                                   (__attribute__((address_space(3))) void*)l, 16, 0, 0);
}

// ---------------------------------------------------------------- fused prep
// r < 2304: x transpose tiles; then Wall rows; projh; Wc rows.
__global__ __launch_bounds__(256) void prep(
    const float* __restrict__ x, const float* __restrict__ wq,
    const float* __restrict__ wk, const float* __restrict__ wv,
    const float* __restrict__ proj, const float* __restrict__ wo,
    const float* __restrict__ bo, const float* __restrict__ wp,
    const float* __restrict__ bp, _Float16* __restrict__ xT,
    _Float16* __restrict__ Wall, _Float16* __restrict__ projh,
    _Float16* __restrict__ Wc, float* __restrict__ bc) {
  __shared__ float T_s[64][65];
  int r = blockIdx.x, t = threadIdx.x;
  if (r < 2304) {
    int nx = r % 144, rem = r / 144;
    int cy = rem & 3, b = rem >> 2;
    int n0 = nx * 64, c0 = cy * 64;
    for (int i = 0; i < 4; ++i) {
      int f = t + i * 256;
      int cc = f >> 4, n4 = f & 15;
      float4 a = *(const float4*)(x + ((size_t)(b * 256 + c0 + cc)) * NTOT + n0 + n4 * 4);
      T_s[cc][n4 * 4 + 0] = a.x;
      T_s[cc][n4 * 4 + 1] = a.y;
      T_s[cc][n4 * 4 + 2] = a.z;
      T_s[cc][n4 * 4 + 3] = a.w;
    }
    __syncthreads();
    for (int i = 0; i < 2; ++i) {
      int f = t + i * 256;
      int nn = f >> 3, c8 = f & 7;
      h8 hv;
      for (int j = 0; j < 8; ++j) hv[j] = (_Float16)T_s[c8 * 8 + j][nn];
      *(h8*)(xT + ((size_t)(b * NTOT + n0 + nn)) * 256 + c0 + c8 * 8) = hv;
    }
    return;
  }
  int r2 = r - 2304;
  if (r2 < 768) {
    const float* src = (r2 < 256) ? wq + (size_t)r2 * 256
                     : (r2 < 512) ? wk + (size_t)(r2 - 256) * 256
                                  : wv + (size_t)(r2 - 512) * 256;
    Wall[(size_t)r2 * 256 + t] = (_Float16)src[t];
  } else if (r2 < 784) {
    int idx = (r2 - 768) * 256 + t;
    projh[idx] = (_Float16)proj[idx];
  } else {
    int o = r2 - 784;
    float acc = 0.f;
    for (int c = 0; c < 256; ++c) acc += wp[o * 256 + c] * wo[c * 256 + t];
    Wc[o * 256 + t] = (_Float16)acc;
    if (t == 0) {
      float ab = bp[o];
      for (int c = 0; c < 256; ++c) ab += wp[o * 256 + c] * bo[c];
      bc[o] = ab;
    }
  }
}

// ---------------------------------------------------------------- qkv MFMA gemm
// R0-proven structure. LDS overlay: ktile (tail-only, 8448 halves) shares the
// pool with A_s/B_s (main-loop-only, 8192 halves) -> LDS 33.3KB -> 16.9KB,
// blocks/CU 4 -> 6 (VGPR-capped at 80). Barrier before first ktile write
// fences the overlay.
__global__ __launch_bounds__(256) void qkv_mfma(
    const _Float16* __restrict__ xT, const _Float16* __restrict__ Wall,
    const _Float16* __restrict__ projh, _Float16* __restrict__ q,
    _Float16* __restrict__ k, _Float16* __restrict__ vT,
    float* __restrict__ kmaxp) {
  __shared__ __align__(16) _Float16 pool[8448];  // A_s[0:4096] B_s[4096:8192] | ktile[0:8448]
  _Float16* A_s = pool;
  _Float16* B_s = pool + 4096;
  _Float16* ktile = pool;
  int bx = blockIdx.x, co0 = blockIdx.y * 128, sel = blockIdx.z;
  int b = bx / 72, ntile = bx % 72;
  int n0 = bx * 128;
  const _Float16* Wb = Wall + (size_t)sel * 65536;
  int t = threadIdx.x, wave = t >> 6, lane = t & 63;
  int lm = lane & 15, lg = lane >> 4;
  int wm = (wave & 1) * 64, wn = (wave >> 1) * 64;
  int srow = wave * 32 + (lane >> 2);
  int scol = ((lane & 3) ^ ((lane >> 3) & 3)) * 8;
  const _Float16* gA = Wb + (size_t)(co0 + srow) * 256 + scol;
  const _Float16* gB = xT + (size_t)(n0 + srow) * 256 + scol;
  _Float16* lA = A_s + wave * 1024;
  _Float16* lB = B_s + wave * 1024;
  int pg = (lg ^ ((lm >> 1) & 3)) * 8;
  f4 acc[4][4] = {};
  if (sel < 2) {
    for (int kt = 0; kt < 8; ++kt) {
      int c0 = kt * 32;
      __syncthreads();
      gld16(gA + c0, lA);
      gld16(gA + c0 + 16 * 256, lA + 512);
      gld16(gB + c0, lB);
      gld16(gB + c0 + 16 * 256, lB + 512);
      __syncthreads();
      h8 a[4], bf[4];
#pragma unroll
      for (int mi = 0; mi < 4; ++mi) a[mi] = *(const h8*)&A_s[(wm + mi * 16 + lm) * 32 + pg];
#pragma unroll
      for (int ni = 0; ni < 4; ++ni) bf[ni] = *(const h8*)&B_s[(wn + ni * 16 + lm) * 32 + pg];
#pragma unroll
      for (int mi = 0; mi < 4; ++mi)
#pragma unroll
        for (int ni = 0; ni < 4; ++ni)
          acc[mi][ni] = __builtin_amdgcn_mfma_f32_16x16x32_f16(a[mi], bf[ni], acc[mi][ni], 0, 0, 0);
    }
    _Float16* Out = (sel == 0) ? q : k;
#pragma unroll
    for (int mi = 0; mi < 4; ++mi)
#pragma unroll
      for (int ni = 0; ni < 4; ++ni) {
        h4 hv;
#pragma unroll
        for (int r = 0; r < 4; ++r) hv[r] = (_Float16)acc[mi][ni][r];
        *(h4*)(Out + (size_t)(n0 + wn + ni * 16 + lm) * 256 + co0 + wm + mi * 16 + lg * 4) = hv;
      }
    if (sel == 1) {
      h8 pr[8];
#pragma unroll
      for (int mt = 0; mt < 8; ++mt)
        pr[mt] = *(const h8*)&projh[(mt * 16 + lm) * 32 + lg * 8];
      float vmax = -1e30f;
      for (int half = 0; half < 2; ++half) {
        __syncthreads();  // also fences the A_s/B_s -> ktile overlay
        if ((wave >> 1) == half) {
#pragma unroll
          for (int mi = 0; mi < 4; ++mi)
#pragma unroll
            for (int ni = 0; ni < 4; ++ni) {
              h4 hv;
#pragma unroll
              for (int r = 0; r < 4; ++r) hv[r] = (_Float16)acc[mi][ni][r];
              *(h4*)&ktile[(ni * 16 + lm) * 132 + wm + mi * 16 + lg * 4] = hv;
            }
        }
        __syncthreads();
#pragma unroll
        for (int nt2 = 0; nt2 < 4; ++nt2) {
          h8 a = *(const h8*)&ktile[(nt2 * 16 + lm) * 132 + wave * 32 + lg * 8];
#pragma unroll
          for (int mt = 0; mt < 8; ++mt) {
            f4 z = {0.f, 0.f, 0.f, 0.f};
            f4 d = __builtin_amdgcn_mfma_f32_16x16x32_f16(a, pr[mt], z, 0, 0, 0);
            vmax = fmaxf(vmax, fmaxf(fmaxf(d[0], d[1]), fmaxf(d[2], d[3])));
          }
        }
      }
      for (int i = 1; i < 64; i <<= 1) vmax = fmaxf(vmax, __shfl_xor(vmax, i, 64));
      if (lane == 0) {
        int h = (co0 >> 5) + wave;
        kmaxp[(size_t)(b * 8 + h) * 72 + ntile] = NORMC * vmax;
      }
    }
  } else {
    for (int kt = 0; kt < 8; ++kt) {
      int c0 = kt * 32;
      __syncthreads();
      gld16(gA + c0, lA);
      gld16(gA + c0 + 16 * 256, lA + 512);
      gld16(gB + c0, lB);
      gld16(gB + c0 + 16 * 256, lB + 512);
      __syncthreads();
      h8 a[4], bf[4];
#pragma unroll
      for (int mi = 0; mi < 4; ++mi) a[mi] = *(const h8*)&A_s[(wm + mi * 16 + lm) * 32 + pg];
#pragma unroll
      for (int ni = 0; ni < 4; ++ni) bf[ni] = *(const h8*)&B_s[(wn + ni * 16 + lm) * 32 + pg];
#pragma unroll
      for (int mi = 0; mi < 4; ++mi)
#pragma unroll
        for (int ni = 0; ni < 4; ++ni)
          acc[mi][ni] = __builtin_amdgcn_mfma_f32_16x16x32_f16(bf[ni], a[mi], acc[mi][ni], 0, 0, 0);
    }
#pragma unroll
    for (int mi = 0; mi < 4; ++mi)
#pragma unroll
      for (int ni = 0; ni < 4; ++ni) {
        h4 hv;
#pragma unroll
        for (int r = 0; r < 4; ++r) hv[r] = (_Float16)acc[mi][ni][r];
        *(h4*)(vT + ((size_t)(b * 256 + co0 + wm + mi * 16 + lm)) * NTOT +
               ntile * 128 + wn + ni * 16 + lg * 4) = hv;
      }
  }
}

// ---------------------------------------------------------------- ctx: partials
// part[blk][d(0..31)][m] = sum_n kp[n][m] v[n][d]; part[blk][32][m] = sum_n kp
__global__ __launch_bounds__(256) void ctx_mfma(
    const _Float16* __restrict__ k, const _Float16* __restrict__ vT,
    const _Float16* __restrict__ projh, const float* __restrict__ kmaxp,
    float* __restrict__ part) {
  __shared__ __align__(16) _Float16 k_s[128 * 32];
  __shared__ __align__(16) _Float16 vT_s[32 * 136];
  __shared__ __align__(16) _Float16 kpT[128 * 136];
  __shared__ float diag_s[128];
  __shared__ float kmax_sh;
  int bh = blockIdx.y, b = bh >> 3, h = bh & 7;
  int nbase = blockIdx.x * 384;
  int t = threadIdx.x, wave = t >> 6, lane = t & 63, lm = lane & 15, lg = lane >> 4;
  h8 pr[8];
#pragma unroll
  for (int mt = 0; mt < 8; ++mt) pr[mt] = *(const h8*)&projh[(mt * 16 + lm) * 32 + lg * 8];
  int scol = ((lane & 3) ^ ((lane >> 3) & 3)) * 8;
  const _Float16* gK =
      k + ((size_t)(b * NTOT + nbase + wave * 32 + (lane >> 2))) * 256 + h * 32 + scol;
  const _Float16* gV = vT + ((size_t)(b * 256 + h * 32 + (t >> 3))) * NTOT + nbase;
  _Float16* lK = k_s + wave * 1024;
  int vd = t >> 3, vg = t & 7;
  // prologue: stage K chunk 0 + gV chunk 0 -> regs (overlaps kmax reduction)
  gld16(gK, lK);
  gld16(gK + 16 * 256, lK + 512);
  h8 vr0 = *(const h8*)(gV + vg * 8);
  h8 vr1 = *(const h8*)(gV + 64 + vg * 8);
  {
    float* kred = (float*)kpT;
    if (t < 72) kred[t] = kmaxp[(size_t)bh * 72 + t];
    __syncthreads();
    if (t == 0) {
      float mx = -1e30f;
      for (int i = 0; i < 72; ++i) mx = fmaxf(mx, kred[i]);
      kmax_sh = mx;
    }
    __syncthreads();
  }
  float kmax = kmax_sh;
  int pg = (lg ^ ((lm >> 1) & 3)) * 8;
  f4 cacc[2][2] = {};
  float ks[8] = {};
#pragma unroll 1
  for (int ch = 0; ch < 3; ++ch) {
    *(h8*)&vT_s[vd * 136 + vg * 8] = vr0;
    *(h8*)&vT_s[vd * 136 + 64 + vg * 8] = vr1;
    asm volatile("s_waitcnt vmcnt(0) lgkmcnt(0)" ::: "memory");  // A: k_s + vT_s ready
    __builtin_amdgcn_s_barrier();
    __builtin_amdgcn_sched_barrier(0);
    if (t < 128) {
      float s = 0.f;
#pragma unroll
      for (int c = 0; c < 4; ++c) {
        h8 kv = *(const h8*)&k_s[t * 32 + c * 8];
#pragma unroll
        for (int j = 0; j < 8; ++j) s += (float)kv[j] * (float)kv[j];
      }
      diag_s[t] = s * (0.5f * NORMC * NORMC);
    }
    f4 dsh[2][8];
#pragma unroll
    for (int nt = 0; nt < 2; ++nt) {
      h8 a = *(const h8*)&k_s[(wave * 32 + nt * 16 + lm) * 32 + pg];
#pragma unroll
      for (int mt = 0; mt < 8; ++mt) {
        f4 z = {0.f, 0.f, 0.f, 0.f};
        dsh[nt][mt] = __builtin_amdgcn_mfma_f32_16x16x32_f16(a, pr[mt], z, 0, 0, 0);
      }
    }
    asm volatile("s_waitcnt lgkmcnt(0)" ::: "memory");  // B: k_s reads + diag write done
    __builtin_amdgcn_s_barrier();
    __builtin_amdgcn_sched_barrier(0);
    if (ch < 2) {  // prefetch next K chunk + next gV (in flight across C, D)
      gld16(gK + (size_t)((ch + 1) * 128) * 256, lK);
      gld16(gK + (size_t)((ch + 1) * 128) * 256 + 16 * 256, lK + 512);
      vr0 = *(const h8*)(gV + (ch + 1) * 128 + vg * 8);
      vr1 = *(const h8*)(gV + (ch + 1) * 128 + 64 + vg * 8);
    }
#pragma unroll
    for (int nt = 0; nt < 2; ++nt)
#pragma unroll
      for (int mt = 0; mt < 8; ++mt) {
        h4 hv;
        float lsum = 0.f;
#pragma unroll
        for (int r = 0; r < 4; ++r) {
          int nl = wave * 32 + nt * 16 + lg * 4 + r;
          float val = RATIO * (__expf(NORMC * dsh[nt][mt][r] - diag_s[nl] - kmax) + FEPS);
          hv[r] = (_Float16)val;
          lsum += val;
        }
        ks[mt] += lsum;
        *(h4*)&kpT[(mt * 16 + lm) * 136 + wave * 32 + nt * 16 + lg * 4] = hv;
      }
    asm volatile("s_waitcnt lgkmcnt(0)" ::: "memory");  // C: kpT visible; vm untouched
    __builtin_amdgcn_s_barrier();
    __builtin_amdgcn_sched_barrier(0);
#pragma unroll
    for (int k2 = 0; k2 < 4; ++k2) {
      h8 a2[2], b2[2];
#pragma unroll
      for (int mt2 = 0; mt2 < 2; ++mt2)
        a2[mt2] = *(const h8*)&kpT[(wave * 32 + mt2 * 16 + lm) * 136 + k2 * 32 + lg * 8];
#pragma unroll
      for (int dt = 0; dt < 2; ++dt)
        b2[dt] = *(const h8*)&vT_s[(dt * 16 + lm) * 136 + k2 * 32 + lg * 8];
#pragma unroll
      for (int mt2 = 0; mt2 < 2; ++mt2)
#pragma unroll
        for (int dt = 0; dt < 2; ++dt)
          cacc[mt2][dt] =
              __builtin_amdgcn_mfma_f32_16x16x32_f16(a2[mt2], b2[dt], cacc[mt2][dt], 0, 0, 0);
    }
    __builtin_amdgcn_s_barrier();  // D: PV reads consumed before vT_s restage
  }
  float* pp = part + (size_t)(blockIdx.y * 24 + blockIdx.x) * 4224;
#pragma unroll
  for (int mt2 = 0; mt2 < 2; ++mt2)
#pragma unroll
    for (int dt = 0; dt < 2; ++dt)
      *(f4*)(pp + (dt * 16 + lm) * 128 + wave * 32 + mt2 * 16 + lg * 4) = cacc[mt2][dt];
  float* redk = (float*)kpT;
#pragma unroll
  for (int mt = 0; mt < 8; ++mt) {
    float s = ks[mt];
    s += __shfl_xor(s, 16, 64);
    s += __shfl_xor(s, 32, 64);
    if (lg == 0) redk[wave * 128 + mt * 16 + lm] = s;
  }
  __syncthreads();
  if (t < 128)
    pp[32 * 128 + t] = redk[t] + redk[128 + t] + redk[256 + t] + redk[384 + t];
}

// ---------------------------------------------------------------- reduce partials
// -> ctxT_g fp16 [bh][d][m], ksum_g f32 [bh][m]
// Regridded 128 -> 1056 blocks (0.5 -> ~4 blocks/CU): one 128-cell row per
// block, 24 independent strided loads per thread.
__global__ __launch_bounds__(128) void reduce_ctx(
    const float* __restrict__ part, _Float16* __restrict__ ctxT_g,
    float* __restrict__ ksum_g) {
  int bh = blockIdx.x / 33, row = blockIdx.x % 33;
  int t = threadIdx.x;
  const float* pb = part + (size_t)bh * 24 * 4224 + row * 128 + t;
  float s = 0.f;
#pragma unroll
  for (int p = 0; p < 24; ++p) s += pb[(size_t)p * 4224];
  if (row < 32) ctxT_g[(size_t)bh * 4096 + row * 128 + t] = (_Float16)s;
  else ksum_g[(size_t)bh * 128 + t] = s;
}

// ---------------------------------------------------------------- q side
// LDS overlay: qp_s (written only after the last q_sh read) shares storage
// with q_sh -> LDS 43.5KB -> 35.3KB, 3 -> 4 blocks/CU. Extra barrier fences
// the overlay.
__global__ __launch_bounds__(256) void attn_mfma(
    const _Float16* __restrict__ q, const _Float16* __restrict__ projh,
    const _Float16* __restrict__ ctxT_g, const float* __restrict__ ksum_g,
    _Float16* __restrict__ attn) {
  __shared__ __align__(16) _Float16 apool[128 * 136];  // q_sh[0:4096] | qp_s[0:17408]
  __shared__ float ksum_s[128];
  _Float16* q_sh = apool;
  _Float16* qp_s = apool;
  int n0 = blockIdx.x * 128;
  int bh = blockIdx.y, b = bh >> 3, h = bh & 7;
  int t = threadIdx.x, wave = t >> 6, lane = t & 63, lm = lane & 15, lg = lane >> 4;
  h8 pr[8];
#pragma unroll
  for (int mt = 0; mt < 8; ++mt) pr[mt] = *(const h8*)&projh[(mt * 16 + lm) * 32 + lg * 8];
  int scol = ((lane & 3) ^ ((lane >> 3) & 3)) * 8;
  const _Float16* gQ =
      q + ((size_t)(b * NTOT + n0 + wave * 32 + (lane >> 2))) * 256 + h * 32 + scol;
  gld16(gQ, q_sh + wave * 1024);
  gld16(gQ + 16 * 256, q_sh + wave * 1024 + 512);
  h8 ac[2][4];
#pragma unroll
  for (int dt = 0; dt < 2; ++dt)
#pragma unroll
    for (int k2 = 0; k2 < 4; ++k2)
      ac[dt][k2] = *(const h8*)&ctxT_g[(size_t)bh * 4096 + (dt * 16 + lm) * 128 + k2 * 32 + lg * 8];
  if (t < 128) ksum_s[t] = ksum_g[(size_t)bh * 128 + t];
  __syncthreads();
  int pg = (lg ^ ((lm >> 1) & 3)) * 8;
  float diag_r[2];
#pragma unroll
  for (int nt = 0; nt < 2; ++nt) {
    int n = wave * 32 + nt * 16 + lm;
    float s = 0.f;
#pragma unroll
    for (int c = 0; c < 4; ++c) {
      h8 qv = *(const h8*)&q_sh[n * 32 + c * 8];
#pragma unroll
      for (int j = 0; j < 8; ++j) s += (float)qv[j] * (float)qv[j];
    }
    diag_r[nt] = s * (0.5f * NORMC * NORMC);
  }
  f4 dsh[2][8];
#pragma unroll
  for (int nt = 0; nt < 2; ++nt) {
    h8 qf = *(const h8*)&q_sh[(wave * 32 + nt * 16 + lm) * 32 + pg];
#pragma unroll
    for (int mt = 0; mt < 8; ++mt) {
      f4 z = {0.f, 0.f, 0.f, 0.f};
      dsh[nt][mt] = __builtin_amdgcn_mfma_f32_16x16x32_f16(pr[mt], qf, z, 0, 0, 0);
    }
  }
  __syncthreads();  // fences the q_sh -> qp_s overlay (all q_sh reads done)
  float den_r[2];
#pragma unroll
  for (int nt = 0; nt < 2; ++nt) {
    float mx = -1e30f;
#pragma unroll
    for (int mt = 0; mt < 8; ++mt)
#pragma unroll
      for (int r = 0; r < 4; ++r) mx = fmaxf(mx, dsh[nt][mt][r]);
    mx = fmaxf(mx, __shfl_xor(mx, 16, 64));
    mx = fmaxf(mx, __shfl_xor(mx, 32, 64));
    float den = 0.f;
#pragma unroll
    for (int mt = 0; mt < 8; ++mt) {
      h4 hv;
#pragma unroll
      for (int r = 0; r < 4; ++r) {
        float val = RATIO * (__expf(NORMC * (dsh[nt][mt][r] - mx) - diag_r[nt]) + FEPS);
        hv[r] = (_Float16)val;
        den += val * ksum_s[mt * 16 + lg * 4 + r];
      }
      *(h4*)&qp_s[(wave * 32 + nt * 16 + lm) * 136 + mt * 16 + lg * 4] = hv;
    }
    den += __shfl_xor(den, 16, 64);
    den += __shfl_xor(den, 32, 64);
    den_r[nt] = 1.f / den;
  }
  __syncthreads();
  f4 oacc[2][2] = {};
#pragma unroll
  for (int k2 = 0; k2 < 4; ++k2) {
    h8 bq[2];
#pragma unroll
    for (int nt = 0; nt < 2; ++nt)
      bq[nt] = *(const h8*)&qp_s[(wave * 32 + nt * 16 + lm) * 136 + k2 * 32 + lg * 8];
#pragma unroll
    for (int dt = 0; dt < 2; ++dt)
#pragma unroll
      for (int nt = 0; nt < 2; ++nt)
        oacc[dt][nt] = __builtin_amdgcn_mfma_f32_16x16x32_f16(ac[dt][k2], bq[nt], oacc[dt][nt], 0, 0, 0);
  }
#pragma unroll
  for (int dt = 0; dt < 2; ++dt)
#pragma unroll
    for (int nt = 0; nt < 2; ++nt) {
      int n = wave * 32 + nt * 16 + lm;
      h4 hv;
#pragma unroll
      for (int r = 0; r < 4; ++r) hv[r] = (_Float16)(oacc[dt][nt][r] * den_r[nt]);
      *(h4*)(attn + ((size_t)(b * NTOT + n0 + n)) * 256 + h * 32 + dt * 16 + lg * 4) = hv;
    }
}

// ---------------------------------------------------------------- output gemm
__global__ __launch_bounds__(256) void out_mfma(
    const _Float16* __restrict__ Wc, const _Float16* __restrict__ attn,
    const float* __restrict__ bc, float* __restrict__ out) {
  __shared__ __align__(16) _Float16 A_s[128 * 32];
  __shared__ __align__(16) _Float16 B_s[128 * 32];
  int bx = blockIdx.x;
  int o0 = blockIdx.y * 128;
  int b = bx / 72, nb0 = (bx % 72) * 128;
  int t = threadIdx.x, wave = t >> 6, lane = t & 63;
  int lm = lane & 15, lg = lane >> 4;
  int wm = (wave & 1) * 64, wn = (wave >> 1) * 64;
  int srow = wave * 32 + (lane >> 2);
  int scol = ((lane & 3) ^ ((lane >> 3) & 3)) * 8;
  const _Float16* gA = Wc + (size_t)(o0 + srow) * 256 + scol;
  const _Float16* gB = attn + (size_t)(b * NTOT + nb0 + srow) * 256 + scol;
  _Float16* lA = A_s + wave * 1024;
  _Float16* lB = B_s + wave * 1024;
  int pg = (lg ^ ((lm >> 1) & 3)) * 8;
  f4 acc[4][4] = {};
  for (int kt = 0; kt < 8; ++kt) {
    int c0 = kt * 32;
    __syncthreads();
    gld16(gA + c0, lA);
    gld16(gA + c0 + 16 * 256, lA + 512);
    gld16(gB + c0, lB);
    gld16(gB + c0 + 16 * 256, lB + 512);
    __syncthreads();
    h8 a[4], bf[4];
#pragma unroll
    for (int mi = 0; mi < 4; ++mi) a[mi] = *(const h8*)&A_s[(wm + mi * 16 + lm) * 32 + pg];
#pragma unroll
    for (int ni = 0; ni < 4; ++ni) bf[ni] = *(const h8*)&B_s[(wn + ni * 16 + lm) * 32 + pg];
#pragma unroll
    for (int mi = 0; mi < 4; ++mi)
#pragma unroll
      for (int ni = 0; ni < 4; ++ni)
        acc[mi][ni] = __builtin_amdgcn_mfma_f32_16x16x32_f16(bf[ni], a[mi], acc[mi][ni], 0, 0, 0);
  }
#pragma unroll
  for (int mi = 0; mi < 4; ++mi) {
    int o = o0 + wm + mi * 16 + lm;
    float bias = bc[o];
#pragma unroll
    for (int ni = 0; ni < 4; ++ni) {
      f4 ov = acc[mi][ni];
      float4 st = make_float4(ov[0] + bias, ov[1] + bias, ov[2] + bias, ov[3] + bias);
      *(float4*)(out + ((size_t)(b * 256 + o)) * NTOT + nb0 + wn + ni * 16 + lg * 4) = st;
    }
  }
}

// ---------------------------------------------------------------- launch
extern "C" void kernel_launch(void* const* d_in, const int* in_sizes, int n_in,
                              void* d_out, int out_size, void* d_ws, size_t ws_size,
                              hipStream_t stream) {
  const float* x = (const float*)d_in[0];
  const float* wq = (const float*)d_in[1];
  const float* wk = (const float*)d_in[2];
  const float* wv = (const float*)d_in[3];
  const float* wo = (const float*)d_in[4];
  const float* bo = (const float*)d_in[5];
  const float* proj = (const float*)d_in[6];
  const float* wp = (const float*)d_in[7];
  const float* bp = (const float*)d_in[8];
  float* out = (float*)d_out;
  float* ws = (float*)d_ws;

  float* part = ws;                        // 768*4224 = 3,244,032
  float* kmaxp = part + 3244032;           // 32*72 = 2304
  float* ksum_g = kmaxp + 2304;            // 32*128 = 4096
  float* bc = ksum_g + 4096;               // 256
  _Float16* hb = (_Float16*)(bc + 256);
  const size_t THALF = (size_t)4 * NTOT * 256;  // 9,437,184
  _Float16* q_h = hb;
  _Float16* k_h = q_h + THALF;
  _Float16* xT = k_h + THALF;          // reused as attn fp16 output
  _Float16* vTg = xT + THALF;          // v transposed [b*256+c][n]
  _Float16* Wall = vTg + THALF;        // 768*256
  _Float16* Wc = Wall + 768 * 256;     // 256*256
  _Float16* projh = Wc + 65536;        // 128*32
  _Float16* ctxT_g = projh + 4096;     // 32*4096

  prep<<<3344, 256, 0, stream>>>(x, wq, wk, wv, proj, wo, bo, wp, bp,
                                 xT, Wall, projh, Wc, bc);
  qkv_mfma<<<dim3(288, 2, 3), 256, 0, stream>>>(xT, Wall, projh, q_h, k_h, vTg, kmaxp);
  ctx_mfma<<<dim3(24, 32), 256, 0, stream>>>(k_h, vTg, projh, kmaxp, part);
  reduce_ctx<<<1056, 128, 0, stream>>>(part, ctxT_g, ksum_g);
  attn_mfma<<<dim3(72, 32), 256, 0, stream>>>(q_h, projh, ctxT_g, ksum_g, xT);
  out_mfma<<<dim3(288, 2), 256, 0, stream>>>(Wc, xT, bc, out);
}

// Round 9
// 212.965 us; speedup vs baseline: 1.1922x; 1.0204x over previous
//
#include <hip/hip_runtime.h>

#define NTOT 9216
#define NORMC 0.42044820762685725f   /* 32^-0.25 */
#define RATIO 0.08838834764831845f   /* 128^-0.5 */
#define FEPS 1e-4f

typedef _Float16 h8 __attribute__((ext_vector_type(8)));
typedef _Float16 h4 __attribute__((ext_vector_type(4)));
typedef float f4 __attribute__((ext_vector_type(4)));

// async global->LDS, 16B/lane; lds dest = wave-uniform base + lane*16
__device__ __forceinline__ void gld16(const _Float16* g, _Float16* l) {
  __builtin_amdgcn_global_load_lds((const __attribute__((address_space(1))) void*)g,
                                   (__attribute__((address_space(3))) void*)l, 16, 0, 0);
}

// ---------------------------------------------------------------- fused prep
// r < 2304: x transpose tiles; then Wall rows; projh; Wc rows.
__global__ __launch_bounds__(256) void prep(
    const float* __restrict__ x, const float* __restrict__ wq,
    const float* __restrict__ wk, const float* __restrict__ wv,
    const float* __restrict__ proj, const float* __restrict__ wo,
    const float* __restrict__ bo, const float* __restrict__ wp,
    const float* __restrict__ bp, _Float16* __restrict__ xT,
    _Float16* __restrict__ Wall, _Float16* __restrict__ projh,
    _Float16* __restrict__ Wc, float* __restrict__ bc) {
  __shared__ float T_s[64][65];
  int r = blockIdx.x, t = threadIdx.x;
  if (r < 2304) {
    int nx = r % 144, rem = r / 144;
    int cy = rem & 3, b = rem >> 2;
    int n0 = nx * 64, c0 = cy * 64;
    for (int i = 0; i < 4; ++i) {
      int f = t + i * 256;
      int cc = f >> 4, n4 = f & 15;
      float4 a = *(const float4*)(x + ((size_t)(b * 256 + c0 + cc)) * NTOT + n0 + n4 * 4);
      T_s[cc][n4 * 4 + 0] = a.x;
      T_s[cc][n4 * 4 + 1] = a.y;
      T_s[cc][n4 * 4 + 2] = a.z;
      T_s[cc][n4 * 4 + 3] = a.w;
    }
    __syncthreads();
    for (int i = 0; i < 2; ++i) {
      int f = t + i * 256;
      int nn = f >> 3, c8 = f & 7;
      h8 hv;
      for (int j = 0; j < 8; ++j) hv[j] = (_Float16)T_s[c8 * 8 + j][nn];
      *(h8*)(xT + ((size_t)(b * NTOT + n0 + nn)) * 256 + c0 + c8 * 8) = hv;
    }
    return;
  }
  int r2 = r - 2304;
  if (r2 < 768) {
    const float* src = (r2 < 256) ? wq + (size_t)r2 * 256
                     : (r2 < 512) ? wk + (size_t)(r2 - 256) * 256
                                  : wv + (size_t)(r2 - 512) * 256;
    Wall[(size_t)r2 * 256 + t] = (_Float16)src[t];
  } else if (r2 < 784) {
    int idx = (r2 - 768) * 256 + t;
    projh[idx] = (_Float16)proj[idx];
  } else {
    int o = r2 - 784;
    float acc = 0.f;
    for (int c = 0; c < 256; ++c) acc += wp[o * 256 + c] * wo[c * 256 + t];
    Wc[o * 256 + t] = (_Float16)acc;
    if (t == 0) {
      float ab = bp[o];
      for (int c = 0; c < 256; ++c) ab += wp[o * 256 + c] * bo[c];
      bc[o] = ab;
    }
  }
}

// ---------------------------------------------------------------- qkv MFMA gemm
// Depth-3 prefetch pipeline: 4 LDS buffers (64 KB), prologue issues tiles
// 0..2; iter t: waitcnt(tile t landed, t+1..t+3 in flight) -> ONE raw
// s_barrier -> issue tile t+3 -> ds_read buf[t&3] -> 16 MFMA. Hide window =
// 3 iterations (~750+ cy) ~ the cold-cache load latency. Reuse safety: tile
// t+4's issue follows barrier(t+1), by which time all waves' reads of
// buf[t&3] (iter t) completed (lgkm waits precede the MFMAs).
// ktile (sel==1 tail) overlays the pool.
__global__ __launch_bounds__(256) void qkv_mfma(
    const _Float16* __restrict__ xT, const _Float16* __restrict__ Wall,
    const _Float16* __restrict__ projh, _Float16* __restrict__ q,
    _Float16* __restrict__ k, _Float16* __restrict__ vT,
    float* __restrict__ kmaxp) {
  __shared__ __align__(16) _Float16 pool[32768];  // 4 x (A[4096] | B[4096]); ktile overlays
  int bx = blockIdx.x, co0 = blockIdx.y * 128, sel = blockIdx.z;
  int b = bx / 72, ntile = bx % 72;
  int n0 = bx * 128;
  const _Float16* Wb = Wall + (size_t)sel * 65536;
  int t = threadIdx.x, wave = t >> 6, lane = t & 63;
  int lm = lane & 15, lg = lane >> 4;
  int wm = (wave & 1) * 64, wn = (wave >> 1) * 64;
  int srow = wave * 32 + (lane >> 2);
  int scol = ((lane & 3) ^ ((lane >> 3) & 3)) * 8;
  const _Float16* gA = Wb + (size_t)(co0 + srow) * 256 + scol;
  const _Float16* gB = xT + (size_t)(n0 + srow) * 256 + scol;
  int so = wave * 1024;
  int pg = (lg ^ ((lm >> 1) & 3)) * 8;
  f4 acc[4][4] = {};
  // prologue: issue tiles 0,1,2 (12 loads/wave outstanding)
#pragma unroll
  for (int p = 0; p < 3; ++p) {
    int c0 = p * 32;
    _Float16* As = pool + p * 8192;
    gld16(gA + c0, As + so);
    gld16(gA + c0 + 16 * 256, As + so + 512);
    gld16(gB + c0, As + 4096 + so);
    gld16(gB + c0 + 16 * 256, As + 4096 + so + 512);
  }
#pragma unroll
  for (int kt = 0; kt < 8; ++kt) {
    // tile kt landed; tiles kt+1..kt+3 (<=8) still in flight across the barrier
    if (kt <= 5) asm volatile("s_waitcnt vmcnt(8)" ::: "memory");
    else if (kt == 6) asm volatile("s_waitcnt vmcnt(4)" ::: "memory");
    else asm volatile("s_waitcnt vmcnt(0)" ::: "memory");
    __builtin_amdgcn_s_barrier();
    __builtin_amdgcn_sched_barrier(0);
    if (kt + 3 < 8) {  // issue tile kt+3 into buf[(kt+3)&3]
      int c0 = (kt + 3) * 32;
      _Float16* As = pool + ((kt + 3) & 3) * 8192;
      gld16(gA + c0, As + so);
      gld16(gA + c0 + 16 * 256, As + so + 512);
      gld16(gB + c0, As + 4096 + so);
      gld16(gB + c0 + 16 * 256, As + 4096 + so + 512);
    }
    const _Float16* As = pool + (kt & 3) * 8192;
    const _Float16* Bs = As + 4096;
    h8 a[4], bf[4];
#pragma unroll
    for (int mi = 0; mi < 4; ++mi) a[mi] = *(const h8*)&As[(wm + mi * 16 + lm) * 32 + pg];
#pragma unroll
    for (int ni = 0; ni < 4; ++ni) bf[ni] = *(const h8*)&Bs[(wn + ni * 16 + lm) * 32 + pg];
    if (sel < 2) {
#pragma unroll
      for (int mi = 0; mi < 4; ++mi)
#pragma unroll
        for (int ni = 0; ni < 4; ++ni)
          acc[mi][ni] = __builtin_amdgcn_mfma_f32_16x16x32_f16(a[mi], bf[ni], acc[mi][ni], 0, 0, 0);
    } else {
#pragma unroll
      for (int mi = 0; mi < 4; ++mi)
#pragma unroll
        for (int ni = 0; ni < 4; ++ni)
          acc[mi][ni] = __builtin_amdgcn_mfma_f32_16x16x32_f16(bf[ni], a[mi], acc[mi][ni], 0, 0, 0);
    }
  }
  if (sel < 2) {
    _Float16* Out = (sel == 0) ? q : k;
#pragma unroll
    for (int mi = 0; mi < 4; ++mi)
#pragma unroll
      for (int ni = 0; ni < 4; ++ni) {
        h4 hv;
#pragma unroll
        for (int r = 0; r < 4; ++r) hv[r] = (_Float16)acc[mi][ni][r];
        *(h4*)(Out + (size_t)(n0 + wn + ni * 16 + lm) * 256 + co0 + wm + mi * 16 + lg * 4) = hv;
      }
    if (sel == 1) {
      _Float16* ktile = pool;  // overlay: pipeline buffers dead here
      h8 pr[8];
#pragma unroll
      for (int mt = 0; mt < 8; ++mt)
        pr[mt] = *(const h8*)&projh[(mt * 16 + lm) * 32 + lg * 8];
      float vmax = -1e30f;
      for (int half = 0; half < 2; ++half) {
        __syncthreads();  // fences pool -> ktile overlay
        if ((wave >> 1) == half) {
#pragma unroll
          for (int mi = 0; mi < 4; ++mi)
#pragma unroll
            for (int ni = 0; ni < 4; ++ni) {
              h4 hv;
#pragma unroll
              for (int r = 0; r < 4; ++r) hv[r] = (_Float16)acc[mi][ni][r];
              *(h4*)&ktile[(ni * 16 + lm) * 132 + wm + mi * 16 + lg * 4] = hv;
            }
        }
        __syncthreads();
#pragma unroll
        for (int nt2 = 0; nt2 < 4; ++nt2) {
          h8 a = *(const h8*)&ktile[(nt2 * 16 + lm) * 132 + wave * 32 + lg * 8];
#pragma unroll
          for (int mt = 0; mt < 8; ++mt) {
            f4 z = {0.f, 0.f, 0.f, 0.f};
            f4 d = __builtin_amdgcn_mfma_f32_16x16x32_f16(a, pr[mt], z, 0, 0, 0);
            vmax = fmaxf(vmax, fmaxf(fmaxf(d[0], d[1]), fmaxf(d[2], d[3])));
          }
        }
      }
      for (int i = 1; i < 64; i <<= 1) vmax = fmaxf(vmax, __shfl_xor(vmax, i, 64));
      if (lane == 0) {
        int h = (co0 >> 5) + wave;
        kmaxp[(size_t)(b * 8 + h) * 72 + ntile] = NORMC * vmax;
      }
    }
  } else {
#pragma unroll
    for (int mi = 0; mi < 4; ++mi)
#pragma unroll
      for (int ni = 0; ni < 4; ++ni) {
        h4 hv;
#pragma unroll
        for (int r = 0; r < 4; ++r) hv[r] = (_Float16)acc[mi][ni][r];
        *(h4*)(vT + ((size_t)(b * 256 + co0 + wm + mi * 16 + lm)) * NTOT +
               ntile * 128 + wn + ni * 16 + lg * 4) = hv;
      }
  }
}

// ---------------------------------------------------------------- ctx: partials
// part[blk][d(0..31)][m] = sum_n kp[n][m] v[n][d]; part[blk][32][m] = sum_n kp
__global__ __launch_bounds__(256) void ctx_mfma(
    const _Float16* __restrict__ k, const _Float16* __restrict__ vT,
    const _Float16* __restrict__ projh, const float* __restrict__ kmaxp,
    float* __restrict__ part) {
  __shared__ __align__(16) _Float16 k_s[128 * 32];
  __shared__ __align__(16) _Float16 vT_s[32 * 136];
  __shared__ __align__(16) _Float16 kpT[128 * 136];
  __shared__ float diag_s[128];
  __shared__ float kmax_sh;
  int bh = blockIdx.y, b = bh >> 3, h = bh & 7;
  int nbase = blockIdx.x * 384;
  int t = threadIdx.x, wave = t >> 6, lane = t & 63, lm = lane & 15, lg = lane >> 4;
  h8 pr[8];
#pragma unroll
  for (int mt = 0; mt < 8; ++mt) pr[mt] = *(const h8*)&projh[(mt * 16 + lm) * 32 + lg * 8];
  int scol = ((lane & 3) ^ ((lane >> 3) & 3)) * 8;
  const _Float16* gK =
      k + ((size_t)(b * NTOT + nbase + wave * 32 + (lane >> 2))) * 256 + h * 32 + scol;
  const _Float16* gV = vT + ((size_t)(b * 256 + h * 32 + (t >> 3))) * NTOT + nbase;
  _Float16* lK = k_s + wave * 1024;
  int vd = t >> 3, vg = t & 7;
  // prologue: stage K chunk 0 + gV chunk 0 -> regs (overlaps kmax reduction)
  gld16(gK, lK);
  gld16(gK + 16 * 256, lK + 512);
  h8 vr0 = *(const h8*)(gV + vg * 8);
  h8 vr1 = *(const h8*)(gV + 64 + vg * 8);
  {
    float* kred = (float*)kpT;
    if (t < 72) kred[t] = kmaxp[(size_t)bh * 72 + t];
    __syncthreads();
    if (t == 0) {
      float mx = -1e30f;
      for (int i = 0; i < 72; ++i) mx = fmaxf(mx, kred[i]);
      kmax_sh = mx;
    }
    __syncthreads();
  }
  float kmax = kmax_sh;
  int pg = (lg ^ ((lm >> 1) & 3)) * 8;
  f4 cacc[2][2] = {};
  float ks[8] = {};
#pragma unroll 1
  for (int ch = 0; ch < 3; ++ch) {
    *(h8*)&vT_s[vd * 136 + vg * 8] = vr0;
    *(h8*)&vT_s[vd * 136 + 64 + vg * 8] = vr1;
    asm volatile("s_waitcnt vmcnt(0) lgkmcnt(0)" ::: "memory");  // A: k_s + vT_s ready
    __builtin_amdgcn_s_barrier();
    __builtin_amdgcn_sched_barrier(0);
    if (t < 128) {
      float s = 0.f;
#pragma unroll
      for (int c = 0; c < 4; ++c) {
        h8 kv = *(const h8*)&k_s[t * 32 + c * 8];
#pragma unroll
        for (int j = 0; j < 8; ++j) s += (float)kv[j] * (float)kv[j];
      }
      diag_s[t] = s * (0.5f * NORMC * NORMC);
    }
    f4 dsh[2][8];
#pragma unroll
    for (int nt = 0; nt < 2; ++nt) {
      h8 a = *(const h8*)&k_s[(wave * 32 + nt * 16 + lm) * 32 + pg];
#pragma unroll
      for (int mt = 0; mt < 8; ++mt) {
        f4 z = {0.f, 0.f, 0.f, 0.f};
        dsh[nt][mt] = __builtin_amdgcn_mfma_f32_16x16x32_f16(a, pr[mt], z, 0, 0, 0);
      }
    }
    asm volatile("s_waitcnt lgkmcnt(0)" ::: "memory");  // B: k_s reads + diag write done
    __builtin_amdgcn_s_barrier();
    __builtin_amdgcn_sched_barrier(0);
    if (ch < 2) {  // prefetch next K chunk + next gV (in flight across C, D)
      gld16(gK + (size_t)((ch + 1) * 128) * 256, lK);
      gld16(gK + (size_t)((ch + 1) * 128) * 256 + 16 * 256, lK + 512);
      vr0 = *(const h8*)(gV + (ch + 1) * 128 + vg * 8);
      vr1 = *(const h8*)(gV + (ch + 1) * 128 + 64 + vg * 8);
    }
#pragma unroll
    for (int nt = 0; nt < 2; ++nt)
#pragma unroll
      for (int mt = 0; mt < 8; ++mt) {
        h4 hv;
        float lsum = 0.f;
#pragma unroll
        for (int r = 0; r < 4; ++r) {
          int nl = wave * 32 + nt * 16 + lg * 4 + r;
          float val = RATIO * (__expf(NORMC * dsh[nt][mt][r] - diag_s[nl] - kmax) + FEPS);
          hv[r] = (_Float16)val;
          lsum += val;
        }
        ks[mt] += lsum;
        *(h4*)&kpT[(mt * 16 + lm) * 136 + wave * 32 + nt * 16 + lg * 4] = hv;
      }
    asm volatile("s_waitcnt lgkmcnt(0)" ::: "memory");  // C: kpT visible; vm untouched
    __builtin_amdgcn_s_barrier();
    __builtin_amdgcn_sched_barrier(0);
#pragma unroll
    for (int k2 = 0; k2 < 4; ++k2) {
      h8 a2[2], b2[2];
#pragma unroll
      for (int mt2 = 0; mt2 < 2; ++mt2)
        a2[mt2] = *(const h8*)&kpT[(wave * 32 + mt2 * 16 + lm) * 136 + k2 * 32 + lg * 8];
#pragma unroll
      for (int dt = 0; dt < 2; ++dt)
        b2[dt] = *(const h8*)&vT_s[(dt * 16 + lm) * 136 + k2 * 32 + lg * 8];
#pragma unroll
      for (int mt2 = 0; mt2 < 2; ++mt2)
#pragma unroll
        for (int dt = 0; dt < 2; ++dt)
          cacc[mt2][dt] =
              __builtin_amdgcn_mfma_f32_16x16x32_f16(a2[mt2], b2[dt], cacc[mt2][dt], 0, 0, 0);
    }
    __builtin_amdgcn_s_barrier();  // D: PV reads consumed before vT_s restage
  }
  float* pp = part + (size_t)(blockIdx.y * 24 + blockIdx.x) * 4224;
#pragma unroll
  for (int mt2 = 0; mt2 < 2; ++mt2)
#pragma unroll
    for (int dt = 0; dt < 2; ++dt)
      *(f4*)(pp + (dt * 16 + lm) * 128 + wave * 32 + mt2 * 16 + lg * 4) = cacc[mt2][dt];
  float* redk = (float*)kpT;
#pragma unroll
  for (int mt = 0; mt < 8; ++mt) {
    float s = ks[mt];
    s += __shfl_xor(s, 16, 64);
    s += __shfl_xor(s, 32, 64);
    if (lg == 0) redk[wave * 128 + mt * 16 + lm] = s;
  }
  __syncthreads();
  if (t < 128)
    pp[32 * 128 + t] = redk[t] + redk[128 + t] + redk[256 + t] + redk[384 + t];
}

// ---------------------------------------------------------------- reduce partials
// -> ctxT_g fp16 [bh][d][m], ksum_g f32 [bh][m]
// 1056 blocks (~4 blocks/CU): one 128-cell row per block.
__global__ __launch_bounds__(128) void reduce_ctx(
    const float* __restrict__ part, _Float16* __restrict__ ctxT_g,
    float* __restrict__ ksum_g) {
  int bh = blockIdx.x / 33, row = blockIdx.x % 33;
  int t = threadIdx.x;
  const float* pb = part + (size_t)bh * 24 * 4224 + row * 128 + t;
  float s = 0.f;
#pragma unroll
  for (int p = 0; p < 24; ++p) s += pb[(size_t)p * 4224];
  if (row < 32) ctxT_g[(size_t)bh * 4096 + row * 128 + t] = (_Float16)s;
  else ksum_g[(size_t)bh * 128 + t] = s;
}

// ---------------------------------------------------------------- q side
// LDS overlay: qp_s shares storage with q_sh (written only after last q_sh
// read; extra barrier fences the overlay).
__global__ __launch_bounds__(256) void attn_mfma(
    const _Float16* __restrict__ q, const _Float16* __restrict__ projh,
    const _Float16* __restrict__ ctxT_g, const float* __restrict__ ksum_g,
    _Float16* __restrict__ attn) {
  __shared__ __align__(16) _Float16 apool[128 * 136];  // q_sh[0:4096] | qp_s[0:17408]
  __shared__ float ksum_s[128];
  _Float16* q_sh = apool;
  _Float16* qp_s = apool;
  int n0 = blockIdx.x * 128;
  int bh = blockIdx.y, b = bh >> 3, h = bh & 7;
  int t = threadIdx.x, wave = t >> 6, lane = t & 63, lm = lane & 15, lg = lane >> 4;
  h8 pr[8];
#pragma unroll
  for (int mt = 0; mt < 8; ++mt) pr[mt] = *(const h8*)&projh[(mt * 16 + lm) * 32 + lg * 8];
  int scol = ((lane & 3) ^ ((lane >> 3) & 3)) * 8;
  const _Float16* gQ =
      q + ((size_t)(b * NTOT + n0 + wave * 32 + (lane >> 2))) * 256 + h * 32 + scol;
  gld16(gQ, q_sh + wave * 1024);
  gld16(gQ + 16 * 256, q_sh + wave * 1024 + 512);
  h8 ac[2][4];
#pragma unroll
  for (int dt = 0; dt < 2; ++dt)
#pragma unroll
    for (int k2 = 0; k2 < 4; ++k2)
      ac[dt][k2] = *(const h8*)&ctxT_g[(size_t)bh * 4096 + (dt * 16 + lm) * 128 + k2 * 32 + lg * 8];
  if (t < 128) ksum_s[t] = ksum_g[(size_t)bh * 128 + t];
  __syncthreads();
  int pg = (lg ^ ((lm >> 1) & 3)) * 8;
  float diag_r[2];
#pragma unroll
  for (int nt = 0; nt < 2; ++nt) {
    int n = wave * 32 + nt * 16 + lm;
    float s = 0.f;
#pragma unroll
    for (int c = 0; c < 4; ++c) {
      h8 qv = *(const h8*)&q_sh[n * 32 + c * 8];
#pragma unroll
      for (int j = 0; j < 8; ++j) s += (float)qv[j] * (float)qv[j];
    }
    diag_r[nt] = s * (0.5f * NORMC * NORMC);
  }
  f4 dsh[2][8];
#pragma unroll
  for (int nt = 0; nt < 2; ++nt) {
    h8 qf = *(const h8*)&q_sh[(wave * 32 + nt * 16 + lm) * 32 + pg];
#pragma unroll
    for (int mt = 0; mt < 8; ++mt) {
      f4 z = {0.f, 0.f, 0.f, 0.f};
      dsh[nt][mt] = __builtin_amdgcn_mfma_f32_16x16x32_f16(pr[mt], qf, z, 0, 0, 0);
    }
  }
  __syncthreads();  // fences the q_sh -> qp_s overlay (all q_sh reads done)
  float den_r[2];
#pragma unroll
  for (int nt = 0; nt < 2; ++nt) {
    float mx = -1e30f;
#pragma unroll
    for (int mt = 0; mt < 8; ++mt)
#pragma unroll
      for (int r = 0; r < 4; ++r) mx = fmaxf(mx, dsh[nt][mt][r]);
    mx = fmaxf(mx, __shfl_xor(mx, 16, 64));
    mx = fmaxf(mx, __shfl_xor(mx, 32, 64));
    float den = 0.f;
#pragma unroll
    for (int mt = 0; mt < 8; ++mt) {
      h4 hv;
#pragma unroll
      for (int r = 0; r < 4; ++r) {
        float val = RATIO * (__expf(NORMC * (dsh[nt][mt][r] - mx) - diag_r[nt]) + FEPS);
        hv[r] = (_Float16)val;
        den += val * ksum_s[mt * 16 + lg * 4 + r];
      }
      *(h4*)&qp_s[(wave * 32 + nt * 16 + lm) * 136 + mt * 16 + lg * 4] = hv;
    }
    den += __shfl_xor(den, 16, 64);
    den += __shfl_xor(den, 32, 64);
    den_r[nt] = 1.f / den;
  }
  __syncthreads();
  f4 oacc[2][2] = {};
#pragma unroll
  for (int k2 = 0; k2 < 4; ++k2) {
    h8 bq[2];
#pragma unroll
    for (int nt = 0; nt < 2; ++nt)
      bq[nt] = *(const h8*)&qp_s[(wave * 32 + nt * 16 + lm) * 136 + k2 * 32 + lg * 8];
#pragma unroll
    for (int dt = 0; dt < 2; ++dt)
#pragma unroll
      for (int nt = 0; nt < 2; ++nt)
        oacc[dt][nt] = __builtin_amdgcn_mfma_f32_16x16x32_f16(ac[dt][k2], bq[nt], oacc[dt][nt], 0, 0, 0);
  }
#pragma unroll
  for (int dt = 0; dt < 2; ++dt)
#pragma unroll
    for (int nt = 0; nt < 2; ++nt) {
      int n = wave * 32 + nt * 16 + lm;
      h4 hv;
#pragma unroll
      for (int r = 0; r < 4; ++r) hv[r] = (_Float16)(oacc[dt][nt][r] * den_r[nt]);
      *(h4*)(attn + ((size_t)(b * NTOT + n0 + n)) * 256 + h * 32 + dt * 16 + lg * 4) = hv;
    }
}

// ---------------------------------------------------------------- output gemm
__global__ __launch_bounds__(256) void out_mfma(
    const _Float16* __restrict__ Wc, const _Float16* __restrict__ attn,
    const float* __restrict__ bc, float* __restrict__ out) {
  __shared__ __align__(16) _Float16 A_s[128 * 32];
  __shared__ __align__(16) _Float16 B_s[128 * 32];
  int bx = blockIdx.x;
  int o0 = blockIdx.y * 128;
  int b = bx / 72, nb0 = (bx % 72) * 128;
  int t = threadIdx.x, wave = t >> 6, lane = t & 63;
  int lm = lane & 15, lg = lane >> 4;
  int wm = (wave & 1) * 64, wn = (wave >> 1) * 64;
  int srow = wave * 32 + (lane >> 2);
  int scol = ((lane & 3) ^ ((lane >> 3) & 3)) * 8;
  const _Float16* gA = Wc + (size_t)(o0 + srow) * 256 + scol;
  const _Float16* gB = attn + (size_t)(b * NTOT + nb0 + srow) * 256 + scol;
  _Float16* lA = A_s + wave * 1024;
  _Float16* lB = B_s + wave * 1024;
  int pg = (lg ^ ((lm >> 1) & 3)) * 8;
  f4 acc[4][4] = {};
  for (int kt = 0; kt < 8; ++kt) {
    int c0 = kt * 32;
    __syncthreads();
    gld16(gA + c0, lA);
    gld16(gA + c0 + 16 * 256, lA + 512);
    gld16(gB + c0, lB);
    gld16(gB + c0 + 16 * 256, lB + 512);
    __syncthreads();
    h8 a[4], bf[4];
#pragma unroll
    for (int mi = 0; mi < 4; ++mi) a[mi] = *(const h8*)&A_s[(wm + mi * 16 + lm) * 32 + pg];
#pragma unroll
    for (int ni = 0; ni < 4; ++ni) bf[ni] = *(const h8*)&B_s[(wn + ni * 16 + lm) * 32 + pg];
#pragma unroll
    for (int mi = 0; mi < 4; ++mi)
#pragma unroll
      for (int ni = 0; ni < 4; ++ni)
        acc[mi][ni] = __builtin_amdgcn_mfma_f32_16x16x32_f16(bf[ni], a[mi], acc[mi][ni], 0, 0, 0);
  }
#pragma unroll
  for (int mi = 0; mi < 4; ++mi) {
    int o = o0 + wm + mi * 16 + lm;
    float bias = bc[o];
#pragma unroll
    for (int ni = 0; ni < 4; ++ni) {
      f4 ov = acc[mi][ni];
      float4 st = make_float4(ov[0] + bias, ov[1] + bias, ov[2] + bias, ov[3] + bias);
      *(float4*)(out + ((size_t)(b * 256 + o)) * NTOT + nb0 + wn + ni * 16 + lg * 4) = st;
    }
  }
}

// ---------------------------------------------------------------- launch
extern "C" void kernel_launch(void* const* d_in, const int* in_sizes, int n_in,
                              void* d_out, int out_size, void* d_ws, size_t ws_size,
                              hipStream_t stream) {
  const float* x = (const float*)d_in[0];
  const float* wq = (const float*)d_in[1];
  const float* wk = (const float*)d_in[2];
  const float* wv = (const float*)d_in[3];
  const float* wo = (const float*)d_in[4];
  const float* bo = (const float*)d_in[5];
  const float* proj = (const float*)d_in[6];
  const float* wp = (const float*)d_in[7];
  const float* bp = (const float*)d_in[8];
  float* out = (float*)d_out;
  float* ws = (float*)d_ws;

  float* part = ws;                        // 768*4224 = 3,244,032
  float* kmaxp = part + 3244032;           // 32*72 = 2304
  float* ksum_g = kmaxp + 2304;            // 32*128 = 4096
  float* bc = ksum_g + 4096;               // 256
  _Float16* hb = (_Float16*)(bc + 256);
  const size_t THALF = (size_t)4 * NTOT * 256;  // 9,437,184
  _Float16* q_h = hb;
  _Float16* k_h = q_h + THALF;
  _Float16* xT = k_h + THALF;          // reused as attn fp16 output
  _Float16* vTg = xT + THALF;          // v transposed [b*256+c][n]
  _Float16* Wall = vTg + THALF;        // 768*256
  _Float16* Wc = Wall + 768 * 256;     // 256*256
  _Float16* projh = Wc + 65536;        // 128*32
  _Float16* ctxT_g = projh + 4096;     // 32*4096

  prep<<<3344, 256, 0, stream>>>(x, wq, wk, wv, proj, wo, bo, wp, bp,
                                 xT, Wall, projh, Wc, bc);
  qkv_mfma<<<dim3(288, 2, 3), 256, 0, stream>>>(xT, Wall, projh, q_h, k_h, vTg, kmaxp);
  ctx_mfma<<<dim3(24, 32), 256, 0, stream>>>(k_h, vTg, projh, kmaxp, part);
  reduce_ctx<<<1056, 128, 0, stream>>>(part, ctxT_g, ksum_g);
  attn_mfma<<<dim3(72, 32), 256, 0, stream>>>(q_h, projh, ctxT_g, ksum_g, xT);
  out_mfma<<<dim3(288, 2), 256, 0, stream>>>(Wc, xT, bc, out);
}